// Round 14
// baseline (696.826 us; speedup 1.0000x reference)
//
#include <hip/hip_runtime.h>
#include <hip/hip_fp16.h>
#include <math.h>
#include <stdint.h>

#define DIM 10
#define NTILE 256
#define BKT_LOG 8
#define BKT 256                   // nodes per bucket
#define NBMAX 2048
#define EPW 2048                  // edges per WG in binning
#define KPT (EPW / 256)
#define NPART 8                   // send partitions (s >> 16 : 64K nodes = 2MB h16)
#define PSHIFT 16
#define CAP 448                   // slots per (partition,bucket) cell: mean 288 + 9.4σ
#define OVFCAP 32768
#define D2WORDS 32768
#define XSTR 11                   // xl LDS stride (coprime with 32 banks)

// meta (u32): cnt[NPART*NBMAX] | ovfc[8] | ovf[OVFCAP] | depth2[D2WORDS]
// ws: h16a[n*16 u16] | h16b[n*16 u16] | bins[NPART*NB*CAP u32] | meta
// x (fp32, stride 10) lives in d_out.

__device__ __forceinline__ float2 cvt2(uint32_t u) {
    __half2 hh = *reinterpret_cast<__half2*>(&u);
    return __half22float2(hh);
}

__device__ __forceinline__ int d2get(const uint32_t* __restrict__ depth2, int node) {
    uint32_t w = depth2[(uint32_t)node >> 4];
    return (int)((w >> ((node & 15) * 2)) & 3u);
}

// ---------------------------------------------------------------------------
// prep: [0,pack) pack depth->2b | [pack,pack+cz) zero counters | rest zero x
// ---------------------------------------------------------------------------
__global__ void prep_kernel(const int* __restrict__ depth,
                            uint32_t* __restrict__ depth2,
                            uint32_t* __restrict__ cnts,     // cnt + ovfc region
                            float4* __restrict__ x4,
                            int n, int pack_blocks, int cnt_tot, int cnt_blocks,
                            int x_tot4)
{
    __shared__ int sd[4096];
    const int t = threadIdx.x;
    const int bid = blockIdx.x;
    if (bid < pack_blocks) {
        const int base = bid * 4096;
        for (int i = t; i < 4096; i += 256) {
            int g = base + i;
            sd[i] = (g < n) ? depth[g] : 3;
        }
        __syncthreads();
        int wb = (base >> 4) + t;
        if (wb * 16 < n) {
            uint32_t v = 0;
            #pragma unroll
            for (int j = 0; j < 16; ++j)
                v |= ((uint32_t)(sd[t * 16 + j] & 3)) << (2 * j);
            depth2[wb] = v;
        }
    } else if (bid < pack_blocks + cnt_blocks) {
        int i = (bid - pack_blocks) * 256 + t;
        if (i < cnt_tot) cnts[i] = 0;
    } else {
        int i = (bid - pack_blocks - cnt_blocks) * 256 + t;
        if (i < x_tot4) x4[i] = make_float4(0.0f, 0.0f, 0.0f, 0.0f);
    }
}

// ---------------------------------------------------------------------------
// binit: blocks [0,bin_blocks) bin edges into (p,b) cells via direct global
// counter atomics (depth2 filter gathers are L2-hot); rest init h16a.
// word = s(19b) | rl(8b)<<19 | flag(useful@iter1)<<27
// ---------------------------------------------------------------------------
__global__ __launch_bounds__(256) void binit_kernel(
                           const int* __restrict__ recv,
                           const int* __restrict__ send,
                           const uint32_t* __restrict__ depth2,
                           const int* __restrict__ depth,
                           const float* __restrict__ h_in,
                           uint16_t* __restrict__ h16a,
                           uint32_t* __restrict__ cnt,
                           uint32_t* __restrict__ ovfc,
                           uint32_t* __restrict__ ovf,
                           uint32_t* __restrict__ bins,
                           int ne, int n, int NB, int bin_blocks)
{
    __shared__ float sh[NTILE * 11];
    const int t = threadIdx.x;
    const int bid = blockIdx.x;

    if (bid < bin_blocks) {
        const int base = bid * EPW;
        int rA[KPT], sA[KPT];
        #pragma unroll
        for (int k = 0; k < KPT; ++k) {
            int e = base + k * 256 + t;
            if (e < ne) { rA[k] = recv[e]; sA[k] = send[e]; }
            else        { rA[k] = -1;      sA[k] = 0;       }
        }
        int drA[KPT], dsA[KPT];
        #pragma unroll
        for (int k = 0; k < KPT; ++k) {
            if (rA[k] >= 0) { drA[k] = d2get(depth2, rA[k]); dsA[k] = d2get(depth2, sA[k]); }
            else            { drA[k] = 3;                    dsA[k] = 3;                    }
        }
        #pragma unroll
        for (int k = 0; k < KPT; ++k) {
            if (rA[k] >= 0 && drA[k] <= 2 && dsA[k] <= 2) {
                int r = rA[k], s = sA[k];
                bool f1 = (drA[k] <= 1) && (dsA[k] <= 1);
                uint32_t w = (uint32_t)s | ((uint32_t)(r & (BKT - 1)) << 19)
                           | (f1 ? (1u << 27) : 0u);
                int cell = (s >> PSHIFT) * NB + (r >> BKT_LOG);
                uint32_t pos = atomicAdd(&cnt[cell], 1u);
                if (pos < CAP) bins[(size_t)cell * CAP + pos] = w;
                else { uint32_t oi = atomicAdd(ovfc, 1u);
                       if (oi < OVFCAP) ovf[oi] = (uint32_t)(base + k * 256 + t); }
            }
        }
    } else {
        // init: h16a[node] = fp16( (depth<=2) ? h_in[node] : 0 ), pads 0
        const int base = (bid - bin_blocks) * NTILE;
        const long gbase = (long)base * DIM;
        const long glim  = (long)n * DIM;
        for (int idx = t; idx < NTILE * DIM; idx += NTILE) {
            long g = gbase + idx;
            float v = (g < glim) ? h_in[g] : 0.0f;
            sh[(idx / DIM) * 11 + (idx % DIM)] = v;
        }
        __syncthreads();
        const int node = base + t;
        if (node < n && depth[node] > 2) {
            #pragma unroll
            for (int c = 0; c < DIM; ++c) sh[t * 11 + c] = 0.0f;
        }
        __syncthreads();
        uint32_t* o16 = reinterpret_cast<uint32_t*>(h16a);
        const long o16base = (long)base * 8;
        const long o16lim  = (long)n * 8;
        for (int idx = t; idx < NTILE * 8; idx += NTILE) {
            long g = o16base + idx;
            if (g < o16lim) {
                int nl = idx / 8, c2 = idx % 8;
                uint32_t w = 0;
                if (c2 < 5) {
                    __half2 hh = __floats2half2_rn(sh[nl * 11 + 2 * c2],
                                                   sh[nl * 11 + 2 * c2 + 1]);
                    w = *reinterpret_cast<uint32_t*>(&hh);
                }
                o16[g] = w;
            }
        }
    }
}

// ---------------------------------------------------------------------------
// partition-phased scatter: blockIdx = p*NB + b (p-major => dispatch order
// phases the send-partitions; gathers hit per-XCD L2). LDS accumulate
// (stride-11), coalesced global-atomic flush into x with zero-skip.
// ---------------------------------------------------------------------------
template<int ITER>
__global__ __launch_bounds__(256) void scat_kernel(
                            const uint32_t* __restrict__ bins,
                            const uint32_t* __restrict__ cnt,
                            const uint16_t* __restrict__ h16,  // stride 16 halfs
                            float* __restrict__ x,             // stride 10 (d_out)
                            int n, int NB)
{
    __shared__ float xl[BKT * XSTR];     // 11264 B
    const int t = threadIdx.x;
    const int cellid = blockIdx.x;       // p * NB + b
    const int b = cellid % NB;
    const int n0 = b << BKT_LOG;
    const int nb = min(BKT, n - n0);

    for (int i = t; i < BKT * XSTR; i += 256) xl[i] = 0.0f;
    __syncthreads();

    const size_t base = (size_t)cellid * CAP;
    const int tot = (int)min(cnt[cellid], (uint32_t)CAP);

    for (int i = t; i < tot; i += 256) {
        uint32_t w = bins[base + i];
        if (ITER == 1 && !((w >> 27) & 1u)) continue;
        size_t s = (size_t)(w & 0x7FFFFu);
        uint4 q = *reinterpret_cast<const uint4*>(h16 + s * 16);
        uint32_t e8 = *reinterpret_cast<const uint32_t*>(h16 + s * 16 + 8);
        float2 f0 = cvt2(q.x), f1 = cvt2(q.y), f2 = cvt2(q.z), f3 = cvt2(q.w);
        float2 f4 = cvt2(e8);
        float* xr = xl + ((w >> 19) & (BKT - 1)) * XSTR;
        atomicAdd(xr + 0, f0.x); atomicAdd(xr + 1, f0.y);
        atomicAdd(xr + 2, f1.x); atomicAdd(xr + 3, f1.y);
        atomicAdd(xr + 4, f2.x); atomicAdd(xr + 5, f2.y);
        atomicAdd(xr + 6, f3.x); atomicAdd(xr + 7, f3.y);
        atomicAdd(xr + 8, f4.x); atomicAdd(xr + 9, f4.y);
    }
    __syncthreads();

    // coalesced atomic flush (skip exact zeros; adding 0 is a no-op anyway)
    float* xo = x + (size_t)n0 * DIM;
    for (int i = t; i < nb * DIM; i += 256) {
        float v = xl[(i / DIM) * XSTR + (i % DIM)];
        if (v != 0.0f) unsafeAtomicAdd(xo + i, v);
    }
}

// ---------------------------------------------------------------------------
// spilled edges -> global atomics on x (rare)
// ---------------------------------------------------------------------------
__global__ void ovf_apply_kernel(const uint32_t* __restrict__ ovfc,
                                 const uint32_t* __restrict__ ovf,
                                 const int* __restrict__ recv,
                                 const int* __restrict__ send,
                                 const int* __restrict__ depth,
                                 const uint16_t* __restrict__ h16,
                                 float* __restrict__ x,
                                 int iter)
{
    const uint32_t cntv = min(*ovfc, (uint32_t)OVFCAP);
    for (uint32_t i = blockIdx.x * blockDim.x + threadIdx.x; i < cntv;
         i += gridDim.x * blockDim.x) {
        int e = (int)ovf[i];
        int r = recv[e], s = send[e];
        if (iter == 1 && (depth[r] > 1 || depth[s] > 1)) continue;
        uint4 q = *reinterpret_cast<const uint4*>(h16 + (size_t)s * 16);
        uint32_t e8 = *reinterpret_cast<const uint32_t*>(h16 + (size_t)s * 16 + 8);
        float2 f0 = cvt2(q.x), f1 = cvt2(q.y), f2 = cvt2(q.z), f3 = cvt2(q.w);
        float2 f4 = cvt2(e8);
        float* xr = x + (size_t)r * DIM;
        unsafeAtomicAdd(xr + 0, f0.x); unsafeAtomicAdd(xr + 1, f0.y);
        unsafeAtomicAdd(xr + 2, f1.x); unsafeAtomicAdd(xr + 3, f1.y);
        unsafeAtomicAdd(xr + 4, f2.x); unsafeAtomicAdd(xr + 5, f2.y);
        unsafeAtomicAdd(xr + 6, f3.x); unsafeAtomicAdd(xr + 7, f3.y);
        unsafeAtomicAdd(xr + 8, f4.x); unsafeAtomicAdd(xr + 9, f4.y);
    }
}

// ---------------------------------------------------------------------------
// GRU node pass. LAST=0: hnext=fp16(gru), mask for iter1, zero x row.
// LAST=1: xio row := gru (in-place read-then-write; same buffer as x/d_out).
// ---------------------------------------------------------------------------
template<int LAST>
__global__ __launch_bounds__(256) void gru_kernel(
                           float* xio,                          // x (d_out), no restrict
                           const uint16_t* __restrict__ hcur,
                           uint16_t* __restrict__ hnext,
                           const int* __restrict__ depth, int n,
                           const float* __restrict__ Wz, const float* __restrict__ bz,
                           const float* __restrict__ Uz, const float* __restrict__ buz,
                           const float* __restrict__ Wr, const float* __restrict__ br,
                           const float* __restrict__ Ur, const float* __restrict__ bur,
                           const float* __restrict__ Wh, const float* __restrict__ bh,
                           const float* __restrict__ Uh, const float* __restrict__ buh)
{
    __shared__ float sW[6][100];
    __shared__ float sb[3][10];
    const int t = threadIdx.x;
    if (t < 100) {
        sW[0][t] = Wz[t]; sW[1][t] = Uz[t];
        sW[2][t] = Wr[t]; sW[3][t] = Ur[t];
        sW[4][t] = Wh[t]; sW[5][t] = Uh[t];
    }
    if (t < 10) {
        sb[0][t] = bz[t] + buz[t];
        sb[1][t] = br[t] + bur[t];
        sb[2][t] = bh[t] + buh[t];
    }
    __syncthreads();

    const int node = blockIdx.x * 256 + t;
    if (node >= n) return;
    const int dep = depth[node];
    const int iter = LAST ? 1 : 0;
    const bool active = (dep + iter) <= 2;

    float hv[DIM];
    {
        const uint16_t* hp = hcur + (size_t)node * 16;
        uint4 q = *reinterpret_cast<const uint4*>(hp);
        uint32_t e8 = *reinterpret_cast<const uint32_t*>(hp + 8);
        float2 f0 = cvt2(q.x), f1 = cvt2(q.y), f2 = cvt2(q.z), f3 = cvt2(q.w);
        float2 f4 = cvt2(e8);
        hv[0] = f0.x; hv[1] = f0.y; hv[2] = f1.x; hv[3] = f1.y;
        hv[4] = f2.x; hv[5] = f2.y; hv[6] = f3.x; hv[7] = f3.y;
        hv[8] = f4.x; hv[9] = f4.y;
    }
    float xv[DIM];
    #pragma unroll
    for (int j = 0; j < DIM; ++j) xv[j] = xio[(size_t)node * DIM + j];

    float outv[DIM];
    if (active) {
        float zz[DIM], rh[DIM];
        #pragma unroll
        for (int i = 0; i < DIM; ++i) {
            float az = sb[0][i], ar = sb[1][i];
            #pragma unroll
            for (int j = 0; j < DIM; ++j) {
                az = fmaf(xv[j], sW[0][i * DIM + j], az);
                az = fmaf(hv[j], sW[1][i * DIM + j], az);
                ar = fmaf(xv[j], sW[2][i * DIM + j], ar);
                ar = fmaf(hv[j], sW[3][i * DIM + j], ar);
            }
            zz[i] = 1.0f / (1.0f + __expf(-az));
            rh[i] = (1.0f / (1.0f + __expf(-ar))) * hv[i];
        }
        #pragma unroll
        for (int i = 0; i < DIM; ++i) {
            float ah = sb[2][i];
            #pragma unroll
            for (int j = 0; j < DIM; ++j) {
                ah = fmaf(xv[j], sW[4][i * DIM + j], ah);
                ah = fmaf(rh[j], sW[5][i * DIM + j], ah);
            }
            outv[i] = zz[i] * hv[i] + (1.0f - zz[i]) * tanhf(ah);
        }
    } else {
        #pragma unroll
        for (int i = 0; i < DIM; ++i) outv[i] = hv[i];   // inactive: h == 0
    }

    if (!LAST) {
        if (dep > 1) {                    // fold iter-1 mask
            #pragma unroll
            for (int i = 0; i < DIM; ++i) outv[i] = 0.0f;
        }
        __half2 h01 = __floats2half2_rn(outv[0], outv[1]);
        __half2 h23 = __floats2half2_rn(outv[2], outv[3]);
        __half2 h45 = __floats2half2_rn(outv[4], outv[5]);
        __half2 h67 = __floats2half2_rn(outv[6], outv[7]);
        __half2 h89 = __floats2half2_rn(outv[8], outv[9]);
        uint4 o0;
        o0.x = *reinterpret_cast<uint32_t*>(&h01);
        o0.y = *reinterpret_cast<uint32_t*>(&h23);
        o0.z = *reinterpret_cast<uint32_t*>(&h45);
        o0.w = *reinterpret_cast<uint32_t*>(&h67);
        uint4 o1;
        o1.x = *reinterpret_cast<uint32_t*>(&h89);
        o1.y = 0; o1.z = 0; o1.w = 0;
        *reinterpret_cast<uint4*>(hnext + (size_t)node * 16)     = o0;
        *reinterpret_cast<uint4*>(hnext + (size_t)node * 16 + 8) = o1;
        #pragma unroll
        for (int j = 0; j < DIM; ++j) xio[(size_t)node * DIM + j] = 0.0f;  // re-zero x
    } else {
        #pragma unroll
        for (int j = 0; j < DIM; ++j) xio[(size_t)node * DIM + j] = outv[j];
    }
}

// ---------------------------------------------------------------------------
// fallback path (ws too small / n too large): fp32 global-atomic pipeline
// ---------------------------------------------------------------------------
__global__ void init_mask32_kernel(const float* __restrict__ hsrc,
                                   float* __restrict__ hdst,
                                   const int* __restrict__ depth, int n)
{
    int node = blockIdx.x * blockDim.x + threadIdx.x;
    if (node >= n) return;
    bool act = depth[node] <= 2;
    const float* s = hsrc + (size_t)node * DIM;
    float* d = hdst + (size_t)node * DIM;
    #pragma unroll
    for (int c = 0; c < DIM; ++c) d[c] = act ? s[c] : 0.0f;
}

__global__ void simple_scatter_kernel(const int* __restrict__ recv,
                                      const int* __restrict__ send,
                                      const float* __restrict__ hm,
                                      float* __restrict__ x, int ne)
{
    const int tid = blockIdx.x * blockDim.x + threadIdx.x;
    const int e = tid / DIM;
    if (e >= ne) return;
    const int c = tid - e * DIM;
    const int s = send[e];
    const float v = hm[(size_t)s * DIM + c];
    if (v != 0.0f) {
        const int r = recv[e];
        unsafeAtomicAdd(x + (size_t)r * DIM + c, v);
    }
}

__global__ void zero_buf_kernel(float4* __restrict__ p, int tot4) {
    int i = blockIdx.x * blockDim.x + threadIdx.x;
    if (i < tot4) p[i] = make_float4(0.0f, 0.0f, 0.0f, 0.0f);
}

__global__ void gru32_kernel(const float* __restrict__ x,
                             const float* __restrict__ h,
                             float* __restrict__ out,
                             const int* __restrict__ depth, int iter, int n,
                             const float* __restrict__ Wz, const float* __restrict__ bz,
                             const float* __restrict__ Uz, const float* __restrict__ buz,
                             const float* __restrict__ Wr, const float* __restrict__ br,
                             const float* __restrict__ Ur, const float* __restrict__ bur,
                             const float* __restrict__ Wh, const float* __restrict__ bh,
                             const float* __restrict__ Uh, const float* __restrict__ buh)
{
    __shared__ float sW[6][100];
    __shared__ float sb[3][10];
    const int t = threadIdx.x;
    if (t < 100) {
        sW[0][t] = Wz[t]; sW[1][t] = Uz[t];
        sW[2][t] = Wr[t]; sW[3][t] = Ur[t];
        sW[4][t] = Wh[t]; sW[5][t] = Uh[t];
    }
    if (t < 10) {
        sb[0][t] = bz[t] + buz[t];
        sb[1][t] = br[t] + bur[t];
        sb[2][t] = bh[t] + buh[t];
    }
    __syncthreads();

    int node = blockIdx.x * blockDim.x + t;
    if (node >= n) return;
    const int dep = depth[node];
    const bool active = dep + iter <= 2;
    float xv[DIM], hv[DIM], outv[DIM];
    #pragma unroll
    for (int j = 0; j < DIM; ++j) {
        xv[j] = x[(size_t)node * DIM + j];
        hv[j] = h[(size_t)node * DIM + j];
    }
    if (active) {
        float zz[DIM], rh[DIM];
        #pragma unroll
        for (int i = 0; i < DIM; ++i) {
            float az = sb[0][i], ar = sb[1][i];
            #pragma unroll
            for (int j = 0; j < DIM; ++j) {
                az = fmaf(xv[j], sW[0][i * DIM + j], az);
                az = fmaf(hv[j], sW[1][i * DIM + j], az);
                ar = fmaf(xv[j], sW[2][i * DIM + j], ar);
                ar = fmaf(hv[j], sW[3][i * DIM + j], ar);
            }
            zz[i] = 1.0f / (1.0f + __expf(-az));
            rh[i] = (1.0f / (1.0f + __expf(-ar))) * hv[i];
        }
        #pragma unroll
        for (int i = 0; i < DIM; ++i) {
            float ah = sb[2][i];
            #pragma unroll
            for (int j = 0; j < DIM; ++j) {
                ah = fmaf(xv[j], sW[4][i * DIM + j], ah);
                ah = fmaf(rh[j], sW[5][i * DIM + j], ah);
            }
            outv[i] = zz[i] * hv[i] + (1.0f - zz[i]) * tanhf(ah);
        }
    } else {
        #pragma unroll
        for (int i = 0; i < DIM; ++i) outv[i] = hv[i];
    }
    if (iter == 0 && dep > 1) {
        #pragma unroll
        for (int i = 0; i < DIM; ++i) outv[i] = 0.0f;
    }
    #pragma unroll
    for (int i = 0; i < DIM; ++i) out[(size_t)node * DIM + i] = outv[i];
}

extern "C" void kernel_launch(void* const* d_in, const int* in_sizes, int n_in,
                              void* d_out, int out_size, void* d_ws, size_t ws_size,
                              hipStream_t stream) {
    const float* h_in  = (const float*)d_in[0];
    const int*   edges = (const int*)d_in[1];
    const int*   depth = (const int*)d_in[2];
    const float* Wz  = (const float*)d_in[3];
    const float* bz  = (const float*)d_in[4];
    const float* Uz  = (const float*)d_in[5];
    const float* buz = (const float*)d_in[6];
    const float* Wr  = (const float*)d_in[7];
    const float* br  = (const float*)d_in[8];
    const float* Ur  = (const float*)d_in[9];
    const float* bur = (const float*)d_in[10];
    const float* Wh  = (const float*)d_in[11];
    const float* bh  = (const float*)d_in[12];
    const float* Uh  = (const float*)d_in[13];
    const float* buh = (const float*)d_in[14];

    const int n  = in_sizes[0] / DIM;       // 500,000
    const int ne = in_sizes[1] / 2;         // 8,000,000
    const int* recv = edges;
    const int* send = edges + ne;

    const int NB = (n + BKT - 1) >> BKT_LOG;
    const size_t meta_words = (size_t)NPART * NBMAX + 8 + OVFCAP + D2WORDS;
    const size_t need = (size_t)n * 16 * sizeof(uint16_t) * 2            // h16a+h16b
                      + (size_t)NPART * NB * CAP * sizeof(uint32_t)      // bins
                      + meta_words * sizeof(uint32_t);

    const int BLK = 256;

    if (ws_size >= need && n <= (1 << 19) && NB <= NBMAX && out_size >= n * DIM) {
        uint16_t* h16a = (uint16_t*)d_ws;
        uint16_t* h16b = h16a + (size_t)n * 16;
        uint32_t* bins = (uint32_t*)(h16b + (size_t)n * 16);
        uint32_t* meta = bins + (size_t)NPART * NB * CAP;
        uint32_t* cnt    = meta;                             // NPART*NBMAX
        uint32_t* ovfc   = meta + (size_t)NPART * NBMAX;     // 8
        uint32_t* ovf    = ovfc + 8;                         // OVFCAP
        uint32_t* depth2 = ovf + OVFCAP;                     // D2WORDS
        float*    x      = (float*)d_out;                    // stride 10

        const int bin_blocks  = (ne + EPW - 1) / EPW;
        const int node_blocks = (n + NTILE - 1) / NTILE;
        const int pack_blocks = (n + 4095) / 4096;
        const int cnt_tot = NPART * NBMAX + 1;
        const int cnt_blocks = (cnt_tot + 255) / 256;
        const int x_tot4 = n * DIM / 4;
        const int x_blocks = (x_tot4 + 255) / 256;

        prep_kernel<<<pack_blocks + cnt_blocks + x_blocks, BLK, 0, stream>>>(
            depth, depth2, cnt, (float4*)x, n, pack_blocks, cnt_tot, cnt_blocks, x_tot4);
        binit_kernel<<<bin_blocks + node_blocks, BLK, 0, stream>>>(
            recv, send, depth2, depth, h_in, h16a,
            cnt, ovfc, ovf, bins, ne, n, NB, bin_blocks);

        // ---- iteration 0 ----
        scat_kernel<0><<<NPART * NB, BLK, 0, stream>>>(bins, cnt, h16a, x, n, NB);
        ovf_apply_kernel<<<16, BLK, 0, stream>>>(ovfc, ovf, recv, send, depth, h16a, x, 0);
        gru_kernel<0><<<node_blocks, BLK, 0, stream>>>(x, h16a, h16b, depth, n,
            Wz, bz, Uz, buz, Wr, br, Ur, bur, Wh, bh, Uh, buh);

        // ---- iteration 1 ----
        scat_kernel<1><<<NPART * NB, BLK, 0, stream>>>(bins, cnt, h16b, x, n, NB);
        ovf_apply_kernel<<<16, BLK, 0, stream>>>(ovfc, ovf, recv, send, depth, h16b, x, 1);
        gru_kernel<1><<<node_blocks, BLK, 0, stream>>>(x, h16b, nullptr, depth, n,
            Wz, bz, Uz, buz, Wr, br, Ur, bur, Wh, bh, Uh, buh);
    } else {
        // fallback: fp32 global-atomic pipeline, h in d_out, x in ws
        float* x    = (float*)d_ws;
        float* hbuf = (float*)d_out;
        const int nwork = ne * DIM;
        const int edge_blocks = (nwork + BLK - 1) / BLK;
        const int x_tot4 = (n * DIM) / 4;
        const int xz_blocks = (x_tot4 + BLK - 1) / BLK;
        const int nb2 = (n + BLK - 1) / BLK;

        init_mask32_kernel<<<nb2, BLK, 0, stream>>>(h_in, hbuf, depth, n);
        zero_buf_kernel<<<xz_blocks, BLK, 0, stream>>>((float4*)x, x_tot4);
        simple_scatter_kernel<<<edge_blocks, BLK, 0, stream>>>(recv, send, hbuf, x, ne);
        gru32_kernel<<<nb2, BLK, 0, stream>>>(x, hbuf, hbuf, depth, 0, n,
            Wz, bz, Uz, buz, Wr, br, Ur, bur, Wh, bh, Uh, buh);
        zero_buf_kernel<<<xz_blocks, BLK, 0, stream>>>((float4*)x, x_tot4);
        simple_scatter_kernel<<<edge_blocks, BLK, 0, stream>>>(recv, send, hbuf, x, ne);
        gru32_kernel<<<nb2, BLK, 0, stream>>>(x, hbuf, hbuf, depth, 1, n,
            Wz, bz, Uz, buz, Wr, br, Ur, bur, Wh, bh, Uh, buh);
    }
}

// Round 15
// 612.374 us; speedup vs baseline: 1.1379x; 1.1379x over previous
//
#include <hip/hip_runtime.h>
#include <hip/hip_fp16.h>
#include <math.h>
#include <stdint.h>

#define DIM 10
#define NTILE 256
#define BKT_LOG 8
#define BKT 256                   // nodes per bucket == threads per WG
#define NBMAX 2048
#define EPW 2048                  // edges per WG in binning
#define KPT (EPW / 256)
#define NPART 8                   // send partitions (s>>16: 64K nodes = 2MB h16)
#define PSHIFT 16
#define CAP 448                   // slots per (p,b) cell: mean 288 + 9.4 sigma
#define OVFCAP 32768
#define D2WORDS 32768
#define XSTR 11                   // xl LDS stride (coprime with 32 banks)

// meta (u32): cnt[NPART*NBMAX] | ovfc[8] | ovf[OVFCAP] | depth2[D2WORDS]
// ws: h16a[n*16 u16] | h16b[n*16 u16] | bins[NPART*NB*CAP u32] | meta
// x never materializes in global memory (LDS-only, fused into GRU).

__device__ __forceinline__ float2 cvt2(uint32_t u) {
    __half2 hh = *reinterpret_cast<__half2*>(&u);
    return __half22float2(hh);
}

__device__ __forceinline__ int d2get(const uint32_t* __restrict__ depth2, int node) {
    uint32_t w = depth2[(uint32_t)node >> 4];
    return (int)((w >> ((node & 15) * 2)) & 3u);
}

// ---------------------------------------------------------------------------
// prep: [0,pack) pack depth->2b | rest zero cell counters + ovfc
// ---------------------------------------------------------------------------
__global__ void prep_kernel(const int* __restrict__ depth,
                            uint32_t* __restrict__ depth2,
                            uint32_t* __restrict__ cnts,
                            int n, int pack_blocks, int cnt_tot)
{
    __shared__ int sd[4096];
    const int t = threadIdx.x;
    const int bid = blockIdx.x;
    if (bid < pack_blocks) {
        const int base = bid * 4096;
        for (int i = t; i < 4096; i += 256) {
            int g = base + i;
            sd[i] = (g < n) ? depth[g] : 3;
        }
        __syncthreads();
        int wb = (base >> 4) + t;
        if (wb * 16 < n) {
            uint32_t v = 0;
            #pragma unroll
            for (int j = 0; j < 16; ++j)
                v |= ((uint32_t)(sd[t * 16 + j] & 3)) << (2 * j);
            depth2[wb] = v;
        }
    } else {
        int i = (bid - pack_blocks) * 256 + t;
        if (i < cnt_tot) cnts[i] = 0;
    }
}

// ---------------------------------------------------------------------------
// binit: blocks [0,bin_blocks) bin edges into (p,b) cells (direct global
// counter atomics; depth2 filter gathers are cache-hot); rest init h16a.
// word = s(19b) | rl(8b)<<19 | flag(useful@iter1)<<27
// ---------------------------------------------------------------------------
__global__ __launch_bounds__(256) void binit_kernel(
                           const int* __restrict__ recv,
                           const int* __restrict__ send,
                           const uint32_t* __restrict__ depth2,
                           const int* __restrict__ depth,
                           const float* __restrict__ h_in,
                           uint16_t* __restrict__ h16a,
                           uint32_t* __restrict__ cnt,
                           uint32_t* __restrict__ ovfc,
                           uint32_t* __restrict__ ovf,
                           uint32_t* __restrict__ bins,
                           int ne, int n, int NB, int bin_blocks)
{
    __shared__ float sh[NTILE * 11];
    const int t = threadIdx.x;
    const int bid = blockIdx.x;

    if (bid < bin_blocks) {
        const int base = bid * EPW;
        int rA[KPT], sA[KPT];
        #pragma unroll
        for (int k = 0; k < KPT; ++k) {
            int e = base + k * 256 + t;
            if (e < ne) { rA[k] = recv[e]; sA[k] = send[e]; }
            else        { rA[k] = -1;      sA[k] = 0;       }
        }
        int drA[KPT], dsA[KPT];
        #pragma unroll
        for (int k = 0; k < KPT; ++k) {
            if (rA[k] >= 0) { drA[k] = d2get(depth2, rA[k]); dsA[k] = d2get(depth2, sA[k]); }
            else            { drA[k] = 3;                    dsA[k] = 3;                    }
        }
        #pragma unroll
        for (int k = 0; k < KPT; ++k) {
            if (rA[k] >= 0 && drA[k] <= 2 && dsA[k] <= 2) {
                int r = rA[k], s = sA[k];
                bool f1 = (drA[k] <= 1) && (dsA[k] <= 1);
                uint32_t w = (uint32_t)s | ((uint32_t)(r & (BKT - 1)) << 19)
                           | (f1 ? (1u << 27) : 0u);
                int cell = (s >> PSHIFT) * NB + (r >> BKT_LOG);
                uint32_t pos = atomicAdd(&cnt[cell], 1u);
                if (pos < CAP) bins[(size_t)cell * CAP + pos] = w;
                else { uint32_t oi = atomicAdd(ovfc, 1u);
                       if (oi < OVFCAP) ovf[oi] = (uint32_t)(base + k * 256 + t); }
            }
        }
    } else {
        // init: h16a[node] = fp16( (depth<=2) ? h_in[node] : 0 ), pads 0
        const int base = (bid - bin_blocks) * NTILE;
        const long gbase = (long)base * DIM;
        const long glim  = (long)n * DIM;
        for (int idx = t; idx < NTILE * DIM; idx += NTILE) {
            long g = gbase + idx;
            float v = (g < glim) ? h_in[g] : 0.0f;
            sh[(idx / DIM) * 11 + (idx % DIM)] = v;
        }
        __syncthreads();
        const int node = base + t;
        if (node < n && depth[node] > 2) {
            #pragma unroll
            for (int c = 0; c < DIM; ++c) sh[t * 11 + c] = 0.0f;
        }
        __syncthreads();
        uint32_t* o16 = reinterpret_cast<uint32_t*>(h16a);
        const long o16base = (long)base * 8;
        const long o16lim  = (long)n * 8;
        for (int idx = t; idx < NTILE * 8; idx += NTILE) {
            long g = o16base + idx;
            if (g < o16lim) {
                int nl = idx / 8, c2 = idx % 8;
                uint32_t w = 0;
                if (c2 < 5) {
                    __half2 hh = __floats2half2_rn(sh[nl * 11 + 2 * c2],
                                                   sh[nl * 11 + 2 * c2 + 1]);
                    w = *reinterpret_cast<uint32_t*>(&hh);
                }
                o16[g] = w;
            }
        }
    }
}

// ---------------------------------------------------------------------------
// fused scatter + GRU, partition-phased soft-lockstep:
// one WG per bucket; loops its 8 (p,b) cells in p order. All ~1954 WGs are
// co-resident (LDS 13.8KB, <=64 VGPR -> 8 WG/CU) and start together, so the
// chip sweeps send-partitions in rough lockstep -> gathers hit per-XCD L2.
// x accumulates purely in LDS; GRU tail consumes it in-register.
// ---------------------------------------------------------------------------
template<int ITER>
__global__ __launch_bounds__(256, 8) void scatgru_kernel(
                            const uint32_t* __restrict__ bins,
                            const uint32_t* __restrict__ cnt,
                            const uint32_t* __restrict__ ovfc,
                            const uint32_t* __restrict__ ovf,
                            const int* __restrict__ recv,
                            const int* __restrict__ send,
                            const int* __restrict__ depth,
                            const uint16_t* __restrict__ hcur,  // stride 16 halfs
                            uint16_t* __restrict__ hnext,       // ITER==0 out
                            float* __restrict__ out32,          // ITER==1 out
                            int n, int NB,
                            const float* __restrict__ Wz, const float* __restrict__ bz,
                            const float* __restrict__ Uz, const float* __restrict__ buz,
                            const float* __restrict__ Wr, const float* __restrict__ br,
                            const float* __restrict__ Ur, const float* __restrict__ bur,
                            const float* __restrict__ Wh, const float* __restrict__ bh,
                            const float* __restrict__ Uh, const float* __restrict__ buh)
{
    __shared__ float xl[BKT * XSTR];     // 11264 B
    __shared__ float sW[6][100];
    __shared__ float sb[3][10];

    const int t = threadIdx.x;
    if (t < 100) {
        sW[0][t] = Wz[t]; sW[1][t] = Uz[t];
        sW[2][t] = Wr[t]; sW[3][t] = Ur[t];
        sW[4][t] = Wh[t]; sW[5][t] = Uh[t];
    }
    if (t < 10) {
        sb[0][t] = bz[t] + buz[t];
        sb[1][t] = br[t] + bur[t];
        sb[2][t] = bh[t] + buh[t];
    }
    for (int i = t; i < BKT * XSTR; i += 256) xl[i] = 0.0f;
    __syncthreads();

    const int b = blockIdx.x;
    const int n0 = b << BKT_LOG;
    const int nb = min(BKT, n - n0);

    // phase 1: partition-ordered gather + LDS accumulate
    for (int p = 0; p < NPART; ++p) {
        const int cell = p * NB + b;
        const size_t base = (size_t)cell * CAP;
        const int tot = (int)min(cnt[cell], (uint32_t)CAP);
        for (int i = t; i < tot; i += 256) {
            uint32_t w = bins[base + i];
            if (ITER == 1 && !((w >> 27) & 1u)) continue;
            size_t s = (size_t)(w & 0x7FFFFu);
            uint4 q = *reinterpret_cast<const uint4*>(hcur + s * 16);
            uint32_t e8 = *reinterpret_cast<const uint32_t*>(hcur + s * 16 + 8);
            float2 f0 = cvt2(q.x), f1 = cvt2(q.y), f2 = cvt2(q.z), f3 = cvt2(q.w);
            float2 f4 = cvt2(e8);
            float* xr = xl + ((w >> 19) & (BKT - 1)) * XSTR;
            atomicAdd(xr + 0, f0.x); atomicAdd(xr + 1, f0.y);
            atomicAdd(xr + 2, f1.x); atomicAdd(xr + 3, f1.y);
            atomicAdd(xr + 4, f2.x); atomicAdd(xr + 5, f2.y);
            atomicAdd(xr + 6, f3.x); atomicAdd(xr + 7, f3.y);
            atomicAdd(xr + 8, f4.x); atomicAdd(xr + 9, f4.y);
        }
    }

    // phase 2: rare overflow edges for this bucket
    {
        const uint32_t cntv = min(*ovfc, (uint32_t)OVFCAP);
        for (uint32_t i = t; i < cntv; i += 256) {
            int e = (int)ovf[i];
            int r = recv[e];
            if ((r >> BKT_LOG) != b) continue;
            int s = send[e];
            if (ITER == 1 && (depth[r] > 1 || depth[s] > 1)) continue;
            uint4 q = *reinterpret_cast<const uint4*>(hcur + (size_t)s * 16);
            uint32_t e8v = *reinterpret_cast<const uint32_t*>(hcur + (size_t)s * 16 + 8);
            float2 f0 = cvt2(q.x), f1 = cvt2(q.y), f2 = cvt2(q.z), f3 = cvt2(q.w);
            float2 f4 = cvt2(e8v);
            float* xr = xl + (r & (BKT - 1)) * XSTR;
            atomicAdd(xr + 0, f0.x); atomicAdd(xr + 1, f0.y);
            atomicAdd(xr + 2, f1.x); atomicAdd(xr + 3, f1.y);
            atomicAdd(xr + 4, f2.x); atomicAdd(xr + 5, f2.y);
            atomicAdd(xr + 6, f3.x); atomicAdd(xr + 7, f3.y);
            atomicAdd(xr + 8, f4.x); atomicAdd(xr + 9, f4.y);
        }
    }
    __syncthreads();

    // phase 3: GRU for node n0+t (register-dieted, proven 40 VGPR)
    if (t < nb) {
        const int node = n0 + t;
        const int dep = depth[node];
        const bool active = (dep + ITER) <= 2;

        float hv[DIM];
        {
            const uint16_t* hp = hcur + (size_t)node * 16;
            uint4 q = *reinterpret_cast<const uint4*>(hp);
            uint32_t e8v = *reinterpret_cast<const uint32_t*>(hp + 8);
            float2 f0 = cvt2(q.x), f1 = cvt2(q.y), f2 = cvt2(q.z), f3 = cvt2(q.w);
            float2 f4 = cvt2(e8v);
            hv[0] = f0.x; hv[1] = f0.y; hv[2] = f1.x; hv[3] = f1.y;
            hv[4] = f2.x; hv[5] = f2.y; hv[6] = f3.x; hv[7] = f3.y;
            hv[8] = f4.x; hv[9] = f4.y;
        }
        float xv[DIM];
        #pragma unroll
        for (int j = 0; j < DIM; ++j) xv[j] = xl[t * XSTR + j];

        float zz[DIM];
        if (active) {
            // pass A: z and r; store r*h into our own xl slots (x consumed)
            #pragma unroll
            for (int i = 0; i < DIM; ++i) {
                float az = sb[0][i];
                float ar = sb[1][i];
                #pragma unroll
                for (int j = 0; j < DIM; ++j) {
                    az = fmaf(xv[j], sW[0][i * DIM + j], az);
                    az = fmaf(hv[j], sW[1][i * DIM + j], az);
                    ar = fmaf(xv[j], sW[2][i * DIM + j], ar);
                    ar = fmaf(hv[j], sW[3][i * DIM + j], ar);
                }
                zz[i] = 1.0f / (1.0f + __expf(-az));
                xl[t * XSTR + i] = (1.0f / (1.0f + __expf(-ar))) * hv[i];  // rh
            }
        }

        if (ITER == 0) {
            uint32_t packed[5];
            float prev = 0.0f;
            #pragma unroll
            for (int i = 0; i < DIM; ++i) {
                float o;
                if (active) {
                    float ah = sb[2][i];
                    #pragma unroll
                    for (int j = 0; j < DIM; ++j) {
                        ah = fmaf(xv[j], sW[4][i * DIM + j], ah);
                        ah = fmaf(xl[t * XSTR + j], sW[5][i * DIM + j], ah);
                    }
                    o = zz[i] * hv[i] + (1.0f - zz[i]) * tanhf(ah);
                } else {
                    o = hv[i];
                }
                if (dep > 1) o = 0.0f;     // fold iter-1 mask
                if (i & 1) {
                    __half2 hh = __floats2half2_rn(prev, o);
                    packed[i >> 1] = *reinterpret_cast<uint32_t*>(&hh);
                } else prev = o;
            }
            uint4 o0 = make_uint4(packed[0], packed[1], packed[2], packed[3]);
            uint4 o1 = make_uint4(packed[4], 0u, 0u, 0u);
            *reinterpret_cast<uint4*>(hnext + (size_t)node * 16)     = o0;
            *reinterpret_cast<uint4*>(hnext + (size_t)node * 16 + 8) = o1;
        } else {
            float2* op = reinterpret_cast<float2*>(out32 + (size_t)node * DIM);
            float prev = 0.0f;
            #pragma unroll
            for (int i = 0; i < DIM; ++i) {
                float o;
                if (active) {
                    float ah = sb[2][i];
                    #pragma unroll
                    for (int j = 0; j < DIM; ++j) {
                        ah = fmaf(xv[j], sW[4][i * DIM + j], ah);
                        ah = fmaf(xl[t * XSTR + j], sW[5][i * DIM + j], ah);
                    }
                    o = zz[i] * hv[i] + (1.0f - zz[i]) * tanhf(ah);
                } else {
                    o = hv[i];
                }
                if (i & 1) op[i >> 1] = make_float2(prev, o);
                else prev = o;
            }
        }
    }
}

// ---------------------------------------------------------------------------
// fallback path (ws too small / n too large): fp32 global-atomic pipeline
// ---------------------------------------------------------------------------
__global__ void init_mask32_kernel(const float* __restrict__ hsrc,
                                   float* __restrict__ hdst,
                                   const int* __restrict__ depth, int n)
{
    int node = blockIdx.x * blockDim.x + threadIdx.x;
    if (node >= n) return;
    bool act = depth[node] <= 2;
    const float* s = hsrc + (size_t)node * DIM;
    float* d = hdst + (size_t)node * DIM;
    #pragma unroll
    for (int c = 0; c < DIM; ++c) d[c] = act ? s[c] : 0.0f;
}

__global__ void simple_scatter_kernel(const int* __restrict__ recv,
                                      const int* __restrict__ send,
                                      const float* __restrict__ hm,
                                      float* __restrict__ x, int ne)
{
    const int tid = blockIdx.x * blockDim.x + threadIdx.x;
    const int e = tid / DIM;
    if (e >= ne) return;
    const int c = tid - e * DIM;
    const int s = send[e];
    const float v = hm[(size_t)s * DIM + c];
    if (v != 0.0f) {
        const int r = recv[e];
        unsafeAtomicAdd(x + (size_t)r * DIM + c, v);
    }
}

__global__ void zero_buf_kernel(float4* __restrict__ p, int tot4) {
    int i = blockIdx.x * blockDim.x + threadIdx.x;
    if (i < tot4) p[i] = make_float4(0.0f, 0.0f, 0.0f, 0.0f);
}

__global__ void gru32_kernel(const float* __restrict__ x,
                             const float* __restrict__ h,
                             float* __restrict__ out,
                             const int* __restrict__ depth, int iter, int n,
                             const float* __restrict__ Wz, const float* __restrict__ bz,
                             const float* __restrict__ Uz, const float* __restrict__ buz,
                             const float* __restrict__ Wr, const float* __restrict__ br,
                             const float* __restrict__ Ur, const float* __restrict__ bur,
                             const float* __restrict__ Wh, const float* __restrict__ bh,
                             const float* __restrict__ Uh, const float* __restrict__ buh)
{
    __shared__ float sW[6][100];
    __shared__ float sb[3][10];
    const int t = threadIdx.x;
    if (t < 100) {
        sW[0][t] = Wz[t]; sW[1][t] = Uz[t];
        sW[2][t] = Wr[t]; sW[3][t] = Ur[t];
        sW[4][t] = Wh[t]; sW[5][t] = Uh[t];
    }
    if (t < 10) {
        sb[0][t] = bz[t] + buz[t];
        sb[1][t] = br[t] + bur[t];
        sb[2][t] = bh[t] + buh[t];
    }
    __syncthreads();

    int node = blockIdx.x * blockDim.x + t;
    if (node >= n) return;
    const int dep = depth[node];
    const bool active = dep + iter <= 2;
    float xv[DIM], hv[DIM], outv[DIM];
    #pragma unroll
    for (int j = 0; j < DIM; ++j) {
        xv[j] = x[(size_t)node * DIM + j];
        hv[j] = h[(size_t)node * DIM + j];
    }
    if (active) {
        float zz[DIM], rh[DIM];
        #pragma unroll
        for (int i = 0; i < DIM; ++i) {
            float az = sb[0][i], ar = sb[1][i];
            #pragma unroll
            for (int j = 0; j < DIM; ++j) {
                az = fmaf(xv[j], sW[0][i * DIM + j], az);
                az = fmaf(hv[j], sW[1][i * DIM + j], az);
                ar = fmaf(xv[j], sW[2][i * DIM + j], ar);
                ar = fmaf(hv[j], sW[3][i * DIM + j], ar);
            }
            zz[i] = 1.0f / (1.0f + __expf(-az));
            rh[i] = (1.0f / (1.0f + __expf(-ar))) * hv[i];
        }
        #pragma unroll
        for (int i = 0; i < DIM; ++i) {
            float ah = sb[2][i];
            #pragma unroll
            for (int j = 0; j < DIM; ++j) {
                ah = fmaf(xv[j], sW[4][i * DIM + j], ah);
                ah = fmaf(rh[j], sW[5][i * DIM + j], ah);
            }
            outv[i] = zz[i] * hv[i] + (1.0f - zz[i]) * tanhf(ah);
        }
    } else {
        #pragma unroll
        for (int i = 0; i < DIM; ++i) outv[i] = hv[i];
    }
    if (iter == 0 && dep > 1) {
        #pragma unroll
        for (int i = 0; i < DIM; ++i) outv[i] = 0.0f;
    }
    #pragma unroll
    for (int i = 0; i < DIM; ++i) out[(size_t)node * DIM + i] = outv[i];
}

extern "C" void kernel_launch(void* const* d_in, const int* in_sizes, int n_in,
                              void* d_out, int out_size, void* d_ws, size_t ws_size,
                              hipStream_t stream) {
    const float* h_in  = (const float*)d_in[0];
    const int*   edges = (const int*)d_in[1];
    const int*   depth = (const int*)d_in[2];
    const float* Wz  = (const float*)d_in[3];
    const float* bz  = (const float*)d_in[4];
    const float* Uz  = (const float*)d_in[5];
    const float* buz = (const float*)d_in[6];
    const float* Wr  = (const float*)d_in[7];
    const float* br  = (const float*)d_in[8];
    const float* Ur  = (const float*)d_in[9];
    const float* bur = (const float*)d_in[10];
    const float* Wh  = (const float*)d_in[11];
    const float* bh  = (const float*)d_in[12];
    const float* Uh  = (const float*)d_in[13];
    const float* buh = (const float*)d_in[14];

    const int n  = in_sizes[0] / DIM;       // 500,000
    const int ne = in_sizes[1] / 2;         // 8,000,000
    const int* recv = edges;
    const int* send = edges + ne;

    const int NB = (n + BKT - 1) >> BKT_LOG;
    const size_t meta_words = (size_t)NPART * NBMAX + 8 + OVFCAP + D2WORDS;
    const size_t need = (size_t)n * 16 * sizeof(uint16_t) * 2            // h16a+h16b
                      + (size_t)NPART * NB * CAP * sizeof(uint32_t)      // bins
                      + meta_words * sizeof(uint32_t);

    const int BLK = 256;

    if (ws_size >= need && n <= (1 << 19) && NB <= NBMAX && out_size >= n * DIM) {
        uint16_t* h16a = (uint16_t*)d_ws;
        uint16_t* h16b = h16a + (size_t)n * 16;
        uint32_t* bins = (uint32_t*)(h16b + (size_t)n * 16);
        uint32_t* meta = bins + (size_t)NPART * NB * CAP;
        uint32_t* cnt    = meta;                             // NPART*NBMAX
        uint32_t* ovfc   = meta + (size_t)NPART * NBMAX;     // 8
        uint32_t* ovf    = ovfc + 8;                         // OVFCAP
        uint32_t* depth2 = ovf + OVFCAP;                     // D2WORDS

        const int bin_blocks  = (ne + EPW - 1) / EPW;
        const int node_blocks = (n + NTILE - 1) / NTILE;
        const int pack_blocks = (n + 4095) / 4096;
        const int cnt_tot = NPART * NBMAX + 1;
        const int cnt_blocks = (cnt_tot + 255) / 256;

        prep_kernel<<<pack_blocks + cnt_blocks, BLK, 0, stream>>>(
            depth, depth2, cnt, n, pack_blocks, cnt_tot);
        binit_kernel<<<bin_blocks + node_blocks, BLK, 0, stream>>>(
            recv, send, depth2, depth, h_in, h16a,
            cnt, ovfc, ovf, bins, ne, n, NB, bin_blocks);

        scatgru_kernel<0><<<NB, BLK, 0, stream>>>(
            bins, cnt, ovfc, ovf, recv, send, depth,
            h16a, h16b, nullptr, n, NB,
            Wz, bz, Uz, buz, Wr, br, Ur, bur, Wh, bh, Uh, buh);

        scatgru_kernel<1><<<NB, BLK, 0, stream>>>(
            bins, cnt, ovfc, ovf, recv, send, depth,
            h16b, nullptr, (float*)d_out, n, NB,
            Wz, bz, Uz, buz, Wr, br, Ur, bur, Wh, bh, Uh, buh);
    } else {
        // fallback: fp32 global-atomic pipeline, h in d_out, x in ws
        float* x    = (float*)d_ws;
        float* hbuf = (float*)d_out;
        const int nwork = ne * DIM;
        const int edge_blocks = (nwork + BLK - 1) / BLK;
        const int x_tot4 = (n * DIM) / 4;
        const int xz_blocks = (x_tot4 + BLK - 1) / BLK;
        const int nb2 = (n + BLK - 1) / BLK;

        init_mask32_kernel<<<nb2, BLK, 0, stream>>>(h_in, hbuf, depth, n);
        zero_buf_kernel<<<xz_blocks, BLK, 0, stream>>>((float4*)x, x_tot4);
        simple_scatter_kernel<<<edge_blocks, BLK, 0, stream>>>(recv, send, hbuf, x, ne);
        gru32_kernel<<<nb2, BLK, 0, stream>>>(x, hbuf, hbuf, depth, 0, n,
            Wz, bz, Uz, buz, Wr, br, Ur, bur, Wh, bh, Uh, buh);
        zero_buf_kernel<<<xz_blocks, BLK, 0, stream>>>((float4*)x, x_tot4);
        simple_scatter_kernel<<<edge_blocks, BLK, 0, stream>>>(recv, send, hbuf, x, ne);
        gru32_kernel<<<nb2, BLK, 0, stream>>>(x, hbuf, hbuf, depth, 1, n,
            Wz, bz, Uz, buz, Wr, br, Ur, bur, Wh, bh, Uh, buh);
    }
}